// Round 7
// baseline (128.265 us; speedup 1.0000x reference)
//
#include <hip/hip_runtime.h>
#include <hip/hip_bf16.h>

#define NB 4
#define NQ 32768
#define NHW 65536
#define NTOK (NB * NQ)

typedef __attribute__((ext_vector_type(8))) short short8;   // 8 bf16 = 4 VGPR (MFMA A/B frag)
typedef __attribute__((ext_vector_type(4))) float f32x4;    // MFMA C/D frag

__device__ __forceinline__ unsigned short f2bf(float f) {
    unsigned int u = __float_as_uint(f);
    u = (u + 0x7FFFu + ((u >> 16) & 1u)) >> 16;   // RNE
    return (unsigned short)u;
}

__device__ __forceinline__ float bflo(unsigned int u) { return __uint_as_float(u << 16); }
__device__ __forceinline__ float bfhi(unsigned int u) { return __uint_as_float(u & 0xffff0000u); }

__device__ __forceinline__ float gelu_tanh(float u) {
    float z = 0.7978845608028654f * (u + 0.044715f * u * u * u);
    float e = __expf(2.0f * z);
    return u - u / (e + 1.0f);   // 0.5*u*(1+tanh(z)), overflow-safe
}

// (B,C,H,W) f32 -> (B,H*W,64) bf16, channel-permuted: chan c -> position p = 4*(c&15) + (c>>4)
__global__ __launch_bounds__(256) void feat_transpose_kernel(
        const float* __restrict__ feat, unsigned int* __restrict__ featT) {
    __shared__ float tile[64][65];
    int blk = blockIdx.x;
    int b = blk >> 10;
    int hw0 = (blk & 1023) << 6;
    int lane = threadIdx.x & 63;
    int row = threadIdx.x >> 6;
    const float* src = feat + ((size_t)b * 64) * NHW + hw0;
    #pragma unroll
    for (int cc = 0; cc < 16; ++cc) {
        int c = (cc << 2) + row;
        tile[c][lane] = src[(size_t)c * NHW + lane];
    }
    __syncthreads();
    unsigned int* dst = featT + ((size_t)(b * NHW + hw0)) * 32;
    #pragma unroll
    for (int it = 0; it < 8; ++it) {
        int flat = it * 256 + threadIdx.x;
        int w = flat >> 5, pp = flat & 31;        // u32 pp covers positions 2pp,2pp+1
        int c1 = (pp >> 1) + 32 * (pp & 1);       // chan of lo; hi chan = c1+16
        unsigned int u;
        asm("v_cvt_pk_bf16_f32 %0, %1, %2" : "=v"(u) : "v"(tile[c1][w]), "v"(tile[c1 + 16][w]));
        dst[(size_t)w * 32 + pp] = u;
    }
}

// Pack 6 weight matrices (64x64 f32 [k][n]) into bf16 B-fragment order with the
// SAME k-permutation as the A staging: k' = p, original k = (p&3)*16 + (p>>2).
__global__ __launch_bounds__(64) void wprep_kernel(
        const float* __restrict__ wq, const float* __restrict__ wk,
        const float* __restrict__ wv, const float* __restrict__ wo,
        const float* __restrict__ wm1, const float* __restrict__ wm2,
        unsigned short* __restrict__ out) {
    int bid = blockIdx.x;               // 48
    int mat = bid >> 3, ti = bid & 7;
    int kt = ti >> 2, nt = ti & 3;
    int l = threadIdx.x;
    const float* W = (mat == 0) ? wq : (mat == 1) ? wk : (mat == 2) ? wv
                   : (mat == 3) ? wo : (mat == 4) ? wm1 : wm2;
    unsigned short* dst = out + ((size_t)(bid) * 64 + l) * 8;
    #pragma unroll
    for (int j = 0; j < 8; ++j) {
        int kp = 8 * (l >> 4) + j + 32 * kt;       // permuted k'
        int k = ((kp & 3) << 4) + (kp >> 2);       // original chan
        int n = (l & 15) + 16 * nt;
        dst[j] = f2bf(W[k * 64 + n]);
    }
}

// One wave = 4 tokens (M=16 rows). Lane = (g = lane>>4 token, li = lane&15).
// D-layout: lane holds rows 4g+i, chans li+16*nt (staged at k'-pos 4li+nt).
// Per-wave LDS 7680B, regions of 80B per (g,head) pair r = 8g+h:
//   Q: [0,2560)   (aliases the 2KB A-frag staging; lifetimes disjoint)
//   K: [2560,5120)
//   P: [5120,7680)
template<bool USE_T>
__global__ __launch_bounds__(256, 2) void token_kernel(
    const float* __restrict__ depth, const float* __restrict__ feat,
    const unsigned int* __restrict__ featT, const float* __restrict__ coord,
    const float* __restrict__ w_ce, const float* __restrict__ b_ce,
    const float* __restrict__ ln1_g, const float* __restrict__ ln1_b,
    const float* __restrict__ b_o, const float* __restrict__ ln2_g,
    const float* __restrict__ ln2_b, const float* __restrict__ b_m1,
    const float* __restrict__ b_m2, const float* __restrict__ w_head,
    const unsigned short* __restrict__ wprep, float* __restrict__ out)
{
    __shared__ char smem[4 * 7680];
    const int wid = threadIdx.x >> 6;
    const int lane = threadIdx.x & 63;
    const int g = lane >> 4;
    const int li = lane & 15;
    const int n = ((blockIdx.x << 2) + wid) * 4 + g;
    const int b = n >> 15;
    char* sb = smem + wid * 7680;

    // ---- distributed gather: each lane computes ONE shifted-coord variant ----
    const float cy0 = coord[2 * n], cx0 = coord[2 * n + 1];
    float relv0, relv1, predv;
    int linv;
    {
        int v = li & 3;
        float vx = (v < 2) ? -1.0f : 1.0f;
        float vy = (v & 1) ? 1.0f : -1.0f;
        float cy = fminf(fmaxf(cy0 + vx * 0.00390625f + 1e-6f, -1.0f + 1e-6f), 1.0f - 1e-6f);
        float cx = fminf(fmaxf(cx0 + vy * 0.00390625f + 1e-6f, -1.0f + 1e-6f), 1.0f - 1e-6f);
        int iy = min(max((int)rintf((cy + 1.0f) * 128.0f - 0.5f), 0), 255);
        int ix = min(max((int)rintf((cx + 1.0f) * 128.0f - 0.5f), 0), 255);
        linv = iy * 256 + ix;
        predv = depth[(b << 16) + linv];
        float ysy = -0.99609375f + 0.0078125f * (float)iy;
        float xsx = -0.99609375f + 0.0078125f * (float)ix;
        relv0 = (cy0 - ysy) * 256.0f;
        relv1 = (cx0 - xsx) * 256.0f;
    }
    const int gbase = lane & 48;     // 16*g

    float wce0[4], wce1[4], bce[4];
    #pragma unroll
    for (int j = 0; j < 4; ++j) {
        wce0[j] = w_ce[li + 16 * j]; wce1[j] = w_ce[64 + li + 16 * j]; bce[j] = b_ce[li + 16 * j];
    }
    float x[4][4];
    #pragma unroll
    for (int i = 0; i < 4; ++i) {
        int lin = __shfl(linv, gbase + i, 64);
        float rel0 = __shfl(relv0, gbase + i, 64);
        float rel1 = __shfl(relv1, gbase + i, 64);
        float t0, t1, t2, t3;
        if (USE_T) {
            uint2 w = *(const uint2*)(featT + ((size_t)((b << 16) + lin)) * 32 + 2 * li);
            t0 = bflo(w.x); t1 = bfhi(w.x); t2 = bflo(w.y); t3 = bfhi(w.y);
        } else {
            t0 = feat[(((size_t)(b * 64 + li)) << 16) + lin];
            t1 = feat[(((size_t)(b * 64 + li + 16)) << 16) + lin];
            t2 = feat[(((size_t)(b * 64 + li + 32)) << 16) + lin];
            t3 = feat[(((size_t)(b * 64 + li + 48)) << 16) + lin];
        }
        x[i][0] = t0 + rel0 * wce0[0] + rel1 * wce1[0] + bce[0];
        x[i][1] = t1 + rel0 * wce0[1] + rel1 * wce1[1] + bce[1];
        x[i][2] = t2 + rel0 * wce0[2] + rel1 * wce1[2] + bce[2];
        x[i][3] = t3 + rel0 * wce0[3] + rel1 * wce1[3] + bce[3];
    }

    // ---- helpers ----
    auto lnorm = [&](float xv[4][4], float hv[4][4],
                     const float* __restrict__ gp, const float* __restrict__ bp) {
        float gj[4], bj[4];
        #pragma unroll
        for (int j = 0; j < 4; ++j) { gj[j] = gp[li + 16 * j]; bj[j] = bp[li + 16 * j]; }
        #pragma unroll
        for (int i = 0; i < 4; ++i) {
            float s = xv[i][0] + xv[i][1] + xv[i][2] + xv[i][3];
            float ss = xv[i][0] * xv[i][0] + xv[i][1] * xv[i][1]
                     + xv[i][2] * xv[i][2] + xv[i][3] * xv[i][3];
            #pragma unroll
            for (int m = 1; m < 16; m <<= 1) {
                s += __shfl_xor(s, m, 64);
                ss += __shfl_xor(ss, m, 64);
            }
            float mean = s * 0.015625f;
            float var = ss * 0.015625f - mean * mean;
            float rs = rsqrtf(var + 1e-5f);
            #pragma unroll
            for (int j = 0; j < 4; ++j)
                hv[i][j] = (xv[i][j] - mean) * rs * gj[j] + bj[j];
        }
    };

    auto put16 = [&](const float v[4][4]) {
        #pragma unroll
        for (int i = 0; i < 4; ++i) {
            int r = 4 * g + i;
            unsigned int u0, u1;
            asm("v_cvt_pk_bf16_f32 %0, %1, %2" : "=v"(u0) : "v"(v[i][0]), "v"(v[i][1]));
            asm("v_cvt_pk_bf16_f32 %0, %1, %2" : "=v"(u1) : "v"(v[i][2]), "v"(v[i][3]));
            *(uint2*)(sb + 128 * r + 16 * (((li >> 1)) ^ (r & 7)) + 8 * (li & 1))
                = make_uint2(u0, u1);
        }
        asm volatile("s_waitcnt lgkmcnt(0)" ::: "memory");
    };
    auto get_frags = [&](short8& a0, short8& a1) {
        a0 = *(const short8*)(sb + 128 * li + 16 * (g ^ (li & 7)));
        a1 = *(const short8*)(sb + 128 * li + 16 * ((4 + g) ^ (li & 7)));
    };

    auto gemm = [&](short8 a0, short8 a1, const short8* __restrict__ Wf, f32x4 acc[4]) {
        #pragma unroll
        for (int nt = 0; nt < 4; ++nt) {
            acc[nt] = __builtin_amdgcn_mfma_f32_16x16x32_bf16(a0, Wf[nt * 64 + lane], acc[nt], 0, 0, 0);
            acc[nt] = __builtin_amdgcn_mfma_f32_16x16x32_bf16(a1, Wf[(4 + nt) * 64 + lane], acc[nt], 0, 0, 0);
        }
    };

    const short8* Wq  = (const short8*)(wprep);
    const short8* Wk  = (const short8*)(wprep + 1 * 4096);
    const short8* Wv  = (const short8*)(wprep + 2 * 4096);
    const short8* Wo  = (const short8*)(wprep + 3 * 4096);
    const short8* Wm1 = (const short8*)(wprep + 4 * 4096);
    const short8* Wm2 = (const short8*)(wprep + 5 * 4096);
    const f32x4 z4 = {0.0f, 0.0f, 0.0f, 0.0f};

    // ---- LN1 + QKV ----
    float h[4][4];
    lnorm(x, h, ln1_g, ln1_b);
    short8 a0, a1;
    put16(h);
    get_frags(a0, a1);
    f32x4 qa[4], ka[4], va[4];
    #pragma unroll
    for (int t = 0; t < 4; ++t) { qa[t] = z4; ka[t] = z4; va[t] = z4; }
    gemm(a0, a1, Wq, qa);
    gemm(a0, a1, Wk, ka);
    gemm(a0, a1, Wv, va);

    // ---- attention stage 1: write Q,K bf16 into per-(g,head) regions [d][t/s] ----
    #pragma unroll
    for (int nt = 0; nt < 4; ++nt) {
        int c = li + 16 * nt;
        int hh = c >> 3;                 // 2nt + (li>>3)
        int d = c & 7;
        int r = 8 * g + hh;
        unsigned int q01, q23, k01, k23;
        asm("v_cvt_pk_bf16_f32 %0, %1, %2" : "=v"(q01) : "v"(qa[nt][0]), "v"(qa[nt][1]));
        asm("v_cvt_pk_bf16_f32 %0, %1, %2" : "=v"(q23) : "v"(qa[nt][2]), "v"(qa[nt][3]));
        asm("v_cvt_pk_bf16_f32 %0, %1, %2" : "=v"(k01) : "v"(ka[nt][0]), "v"(ka[nt][1]));
        asm("v_cvt_pk_bf16_f32 %0, %1, %2" : "=v"(k23) : "v"(ka[nt][2]), "v"(ka[nt][3]));
        int off = r * 80 + ((((d >> 1) + g) & 3) << 4) + ((d & 1) << 3);
        *(uint2*)(sb + off)        = make_uint2(q01, q23);
        *(uint2*)(sb + 2560 + off) = make_uint2(k01, k23);
    }
    asm volatile("s_waitcnt lgkmcnt(0)" ::: "memory");

    // ---- stage 2: unit (g, head hp, t-half hf) computes S + softmax, writes P f32 ----
    {
        const int hp = li >> 1, hf = li & 1;
        const int ru = 8 * g + hp;
        float kk[8][4], qq[8][2];
        #pragma unroll
        for (int j = 0; j < 4; ++j) {
            int slot = (((j + g) & 3) << 4);
            const char* kb = sb + 2560 + ru * 80 + slot;
            uint4 kv = *(const uint4*)kb;
            kk[2 * j][0] = bflo(kv.x); kk[2 * j][1] = bfhi(kv.x);
            kk[2 * j][2] = bflo(kv.y); kk[2 * j][3] = bfhi(kv.y);
            kk[2 * j + 1][0] = bflo(kv.z); kk[2 * j + 1][1] = bfhi(kv.z);
            kk[2 * j + 1][2] = bflo(kv.w); kk[2 * j + 1][3] = bfhi(kv.w);
            const char* qb = sb + ru * 80 + slot + (hf << 2);
            unsigned int qv0 = *(const unsigned int*)qb;
            unsigned int qv1 = *(const unsigned int*)(qb + 8);
            qq[2 * j][0] = bflo(qv0); qq[2 * j][1] = bfhi(qv0);
            qq[2 * j + 1][0] = bflo(qv1); qq[2 * j + 1][1] = bfhi(qv1);
        }
        float S[2][4];
        #pragma unroll
        for (int tl = 0; tl < 2; ++tl)
            #pragma unroll
            for (int s = 0; s < 4; ++s) {
                float acc = qq[0][tl] * kk[0][s];
                #pragma unroll
                for (int d = 1; d < 8; ++d) acc += qq[d][tl] * kk[d][s];
                S[tl][s] = acc;
            }
        #pragma unroll
        for (int tl = 0; tl < 2; ++tl) {
            float m = fmaxf(fmaxf(S[tl][0], S[tl][1]), fmaxf(S[tl][2], S[tl][3]));
            float e0 = __expf((S[tl][0] - m) * 0.35355339059327378f);
            float e1 = __expf((S[tl][1] - m) * 0.35355339059327378f);
            float e2 = __expf((S[tl][2] - m) * 0.35355339059327378f);
            float e3 = __expf((S[tl][3] - m) * 0.35355339059327378f);
            float inv = 1.0f / (e0 + e1 + e2 + e3);
            f32x4 p = {e0 * inv, e1 * inv, e2 * inv, e3 * inv};
            int t = 2 * hf + tl;
            *(f32x4*)(sb + 5120 + ru * 80 + (((t + g) & 3) << 4)) = p;
        }
    }
    asm volatile("s_waitcnt lgkmcnt(0)" ::: "memory");

    // ---- stage 3: every lane reads P for its 4 heads; O lane-local from va ----
    float o2[4][4];   // [pos t][nt], D-layout
    #pragma unroll
    for (int nt = 0; nt < 4; ++nt) {
        int r = 8 * g + 2 * nt + (li >> 3);
        const char* pb = sb + 5120 + r * 80;
        #pragma unroll
        for (int t = 0; t < 4; ++t) {
            f32x4 pr = *(const f32x4*)(pb + (((t + g) & 3) << 4));
            o2[t][nt] = pr[0] * va[nt][0] + pr[1] * va[nt][1]
                      + pr[2] * va[nt][2] + pr[3] * va[nt][3];
        }
    }

    // ---- o @ w_o + b_o + residual ----
    put16(o2);
    get_frags(a0, a1);
    f32x4 oa[4];
    #pragma unroll
    for (int t = 0; t < 4; ++t) oa[t] = z4;
    gemm(a0, a1, Wo, oa);
    {
        float bo[4];
        #pragma unroll
        for (int j = 0; j < 4; ++j) bo[j] = b_o[li + 16 * j];
        #pragma unroll
        for (int i = 0; i < 4; ++i)
            #pragma unroll
            for (int j = 0; j < 4; ++j) x[i][j] += oa[j][i] + bo[j];
    }

    // ---- LN2 + MLP ----
    float h2[4][4];
    lnorm(x, h2, ln2_g, ln2_b);
    put16(h2);
    get_frags(a0, a1);
    f32x4 ma[4];
    #pragma unroll
    for (int t = 0; t < 4; ++t) ma[t] = z4;
    gemm(a0, a1, Wm1, ma);
    float g1[4][4];
    {
        float bm[4];
        #pragma unroll
        for (int j = 0; j < 4; ++j) bm[j] = b_m1[li + 16 * j];
        #pragma unroll
        for (int i = 0; i < 4; ++i)
            #pragma unroll
            for (int j = 0; j < 4; ++j) g1[i][j] = gelu_tanh(ma[j][i] + bm[j]);
    }
    put16(g1);
    get_frags(a0, a1);
    f32x4 m2a[4];
    #pragma unroll
    for (int t = 0; t < 4; ++t) m2a[t] = z4;
    gemm(a0, a1, Wm2, m2a);
    {
        float bm[4];
        #pragma unroll
        for (int j = 0; j < 4; ++j) bm[j] = b_m2[li + 16 * j];
        #pragma unroll
        for (int i = 0; i < 4; ++i)
            #pragma unroll
            for (int j = 0; j < 4; ++j) x[i][j] += m2a[j][i] + bm[j];
    }

    // ---- head softmax over 4 positions; weighted depth blend ----
    float wh[4];
    #pragma unroll
    for (int j = 0; j < 4; ++j) wh[j] = w_head[li + 16 * j];
    float lg[4];
    #pragma unroll
    for (int i = 0; i < 4; ++i) {
        float s = x[i][0] * wh[0] + x[i][1] * wh[1] + x[i][2] * wh[2] + x[i][3] * wh[3];
        #pragma unroll
        for (int m = 1; m < 16; m <<= 1) s += __shfl_xor(s, m, 64);
        lg[i] = s;
    }
    float m = fmaxf(fmaxf(lg[0], lg[1]), fmaxf(lg[2], lg[3]));
    float e0 = __expf(lg[0] - m), e1 = __expf(lg[1] - m);
    float e2 = __expf(lg[2] - m), e3 = __expf(lg[3] - m);
    float p0 = __shfl(predv, gbase + 0, 64);
    float p1 = __shfl(predv, gbase + 1, 64);
    float p2 = __shfl(predv, gbase + 2, 64);
    float p3 = __shfl(predv, gbase + 3, 64);
    float res = (p0 * e0 + p1 * e1 + p2 * e2 + p3 * e3) / (e0 + e1 + e2 + e3);
    if (li == 0) out[n] = res;
}

extern "C" void kernel_launch(void* const* d_in, const int* in_sizes, int n_in,
                              void* d_out, int out_size, void* d_ws, size_t ws_size,
                              hipStream_t stream) {
    const float* depth  = (const float*)d_in[0];
    const float* feat   = (const float*)d_in[1];
    const float* coord  = (const float*)d_in[2];
    const float* w_ce   = (const float*)d_in[3];
    const float* b_ce   = (const float*)d_in[4];
    const float* ln1_g  = (const float*)d_in[5];
    const float* ln1_b  = (const float*)d_in[6];
    const float* w_q    = (const float*)d_in[7];
    const float* w_k    = (const float*)d_in[8];
    const float* w_v    = (const float*)d_in[9];
    const float* w_o    = (const float*)d_in[10];
    const float* b_o    = (const float*)d_in[11];
    const float* ln2_g  = (const float*)d_in[12];
    const float* ln2_b  = (const float*)d_in[13];
    const float* w_m1   = (const float*)d_in[14];
    const float* b_m1   = (const float*)d_in[15];
    const float* w_m2   = (const float*)d_in[16];
    const float* b_m2   = (const float*)d_in[17];
    const float* w_head = (const float*)d_in[18];
    float* outp = (float*)d_out;

    unsigned short* wprep = (unsigned short*)d_ws;
    const size_t FEATT_OFF = 65536;                           // wprep uses 49152 B
    const size_t featT_bytes = (size_t)NB * NHW * 64 * 2;     // bf16
    unsigned int* featT = (unsigned int*)((char*)d_ws + FEATT_OFF);
    bool use_t = (d_ws != nullptr) && (ws_size >= FEATT_OFF + featT_bytes);

    wprep_kernel<<<48, 64, 0, stream>>>(w_q, w_k, w_v, w_o, w_m1, w_m2, wprep);
    if (use_t) {
        feat_transpose_kernel<<<NB * (NHW / 64), 256, 0, stream>>>(feat, featT);
        token_kernel<true><<<NTOK / 16, 256, 0, stream>>>(
            depth, feat, featT, coord, w_ce, b_ce, ln1_g, ln1_b,
            b_o, ln2_g, ln2_b, b_m1, b_m2, w_head, wprep, outp);
    } else {
        token_kernel<false><<<NTOK / 16, 256, 0, stream>>>(
            depth, feat, featT, coord, w_ce, b_ce, ln1_g, ln1_b,
            b_o, ln2_g, ln2_b, b_m1, b_m2, w_head, wprep, outp);
    }
}

// Round 9
// 120.985 us; speedup vs baseline: 1.0602x; 1.0602x over previous
//
#include <hip/hip_runtime.h>
#include <hip/hip_bf16.h>

#define NB 4
#define NQ 32768
#define NHW 65536
#define NTOK (NB * NQ)

typedef __attribute__((ext_vector_type(8))) short short8;   // 8 bf16 = 4 VGPR (MFMA A/B frag)
typedef __attribute__((ext_vector_type(4))) float f32x4;    // MFMA C/D frag

__device__ __forceinline__ unsigned short f2bf(float f) {
    unsigned int u = __float_as_uint(f);
    u = (u + 0x7FFFu + ((u >> 16) & 1u)) >> 16;   // RNE
    return (unsigned short)u;
}

__device__ __forceinline__ float bflo(unsigned int u) { return __uint_as_float(u << 16); }
__device__ __forceinline__ float bfhi(unsigned int u) { return __uint_as_float(u & 0xffff0000u); }

__device__ __forceinline__ float gelu_tanh(float u) {
    float z = 0.7978845608028654f * (u + 0.044715f * u * u * u);
    float e = __expf(2.0f * z);
    return u - u / (e + 1.0f);   // 0.5*u*(1+tanh(z)), overflow-safe
}

// (B,C,H,W) f32 -> (B,H*W,64) bf16, channel-permuted: chan c -> position p = 4*(c&15) + (c>>4)
__global__ __launch_bounds__(256) void feat_transpose_kernel(
        const float* __restrict__ feat, unsigned int* __restrict__ featT) {
    __shared__ float tile[64][65];
    int blk = blockIdx.x;
    int b = blk >> 10;
    int hw0 = (blk & 1023) << 6;
    int lane = threadIdx.x & 63;
    int row = threadIdx.x >> 6;
    const float* src = feat + ((size_t)b * 64) * NHW + hw0;
    #pragma unroll
    for (int cc = 0; cc < 16; ++cc) {
        int c = (cc << 2) + row;
        tile[c][lane] = src[(size_t)c * NHW + lane];
    }
    __syncthreads();
    unsigned int* dst = featT + ((size_t)(b * NHW + hw0)) * 32;
    #pragma unroll
    for (int it = 0; it < 8; ++it) {
        int flat = it * 256 + threadIdx.x;
        int w = flat >> 5, pp = flat & 31;        // u32 pp covers positions 2pp,2pp+1
        int c1 = (pp >> 1) + 32 * (pp & 1);       // chan of lo; hi chan = c1+16
        unsigned int u;
        asm("v_cvt_pk_bf16_f32 %0, %1, %2" : "=v"(u) : "v"(tile[c1][w]), "v"(tile[c1 + 16][w]));
        dst[(size_t)w * 32 + pp] = u;
    }
}

// Pack 6 weight matrices (64x64 f32 [k][n]) into bf16 B-fragment order with the
// k' permutation: k' = p, original k = (p&3)*16 + (p>>2).  (No folding — R6 form.)
__global__ __launch_bounds__(64) void wprep_kernel(
        const float* __restrict__ wq, const float* __restrict__ wk,
        const float* __restrict__ wv, const float* __restrict__ wo,
        const float* __restrict__ wm1, const float* __restrict__ wm2,
        unsigned short* __restrict__ out) {
    int bid = blockIdx.x;               // 48
    int mat = bid >> 3, ti = bid & 7;
    int kt = ti >> 2, nt = ti & 3;
    int l = threadIdx.x;
    const float* W = (mat == 0) ? wq : (mat == 1) ? wk : (mat == 2) ? wv
                   : (mat == 3) ? wo : (mat == 4) ? wm1 : wm2;
    unsigned short* dst = out + ((size_t)(bid) * 64 + l) * 8;
    #pragma unroll
    for (int j = 0; j < 8; ++j) {
        int kp = 8 * (l >> 4) + j + 32 * kt;       // permuted k'
        int k = ((kp & 3) << 4) + (kp >> 2);       // original chan
        int n = (l & 15) + 16 * nt;
        dst[j] = f2bf(W[k * 64 + n]);
    }
}

// One wave = 4 tokens (M=16 rows). Lane = (g = lane>>4 token, li = lane&15).
// D-layout: lane holds rows 4g+i, chans li+16*nt (staged at k'-pos 4li+nt).
// Per-wave LDS 6KB: [0,2KB) A-frag staging (aliases Q attn staging),
//                   [2KB,4KB) K staging, [4KB,6KB) V staging — all bf16.
template<bool USE_T>
__global__ __launch_bounds__(256, 2) void token_kernel(
    const float* __restrict__ depth, const float* __restrict__ feat,
    const unsigned int* __restrict__ featT, const float* __restrict__ coord,
    const float* __restrict__ w_ce, const float* __restrict__ b_ce,
    const float* __restrict__ ln1_g, const float* __restrict__ ln1_b,
    const float* __restrict__ b_o, const float* __restrict__ ln2_g,
    const float* __restrict__ ln2_b, const float* __restrict__ b_m1,
    const float* __restrict__ b_m2, const float* __restrict__ w_head,
    const unsigned short* __restrict__ wprep, float* __restrict__ out)
{
    __shared__ char smem[4 * 6144];
    const int wid = threadIdx.x >> 6;
    const int lane = threadIdx.x & 63;
    const int g = lane >> 4;
    const int li = lane & 15;
    const int n = ((blockIdx.x << 2) + wid) * 4 + g;
    const int b = n >> 15;
    char* sb = smem + wid * 6144;

    // ---- distributed gather: each lane computes ONE shifted-coord variant (R7, proven) ----
    const float cy0 = coord[2 * n], cx0 = coord[2 * n + 1];
    float relv0, relv1, predv;
    int linv;
    {
        int v = li & 3;
        float vx = (v < 2) ? -1.0f : 1.0f;
        float vy = (v & 1) ? 1.0f : -1.0f;
        float cy = fminf(fmaxf(cy0 + vx * 0.00390625f + 1e-6f, -1.0f + 1e-6f), 1.0f - 1e-6f);
        float cx = fminf(fmaxf(cx0 + vy * 0.00390625f + 1e-6f, -1.0f + 1e-6f), 1.0f - 1e-6f);
        int iy = min(max((int)rintf((cy + 1.0f) * 128.0f - 0.5f), 0), 255);
        int ix = min(max((int)rintf((cx + 1.0f) * 128.0f - 0.5f), 0), 255);
        linv = iy * 256 + ix;
        predv = depth[(b << 16) + linv];
        float ysy = -0.99609375f + 0.0078125f * (float)iy;
        float xsx = -0.99609375f + 0.0078125f * (float)ix;
        relv0 = (cy0 - ysy) * 256.0f;
        relv1 = (cx0 - xsx) * 256.0f;
    }
    const int gbase = lane & 48;     // 16*g

    float wce0[4], wce1[4], bce[4];
    #pragma unroll
    for (int j = 0; j < 4; ++j) {
        wce0[j] = w_ce[li + 16 * j]; wce1[j] = w_ce[64 + li + 16 * j]; bce[j] = b_ce[li + 16 * j];
    }
    float x[4][4];
    #pragma unroll
    for (int i = 0; i < 4; ++i) {
        int lin = __shfl(linv, gbase + i, 64);
        float rel0 = __shfl(relv0, gbase + i, 64);
        float rel1 = __shfl(relv1, gbase + i, 64);
        float t0, t1, t2, t3;
        if (USE_T) {
            uint2 w = *(const uint2*)(featT + ((size_t)((b << 16) + lin)) * 32 + 2 * li);
            t0 = bflo(w.x); t1 = bfhi(w.x); t2 = bflo(w.y); t3 = bfhi(w.y);
        } else {
            t0 = feat[(((size_t)(b * 64 + li)) << 16) + lin];
            t1 = feat[(((size_t)(b * 64 + li + 16)) << 16) + lin];
            t2 = feat[(((size_t)(b * 64 + li + 32)) << 16) + lin];
            t3 = feat[(((size_t)(b * 64 + li + 48)) << 16) + lin];
        }
        x[i][0] = t0 + rel0 * wce0[0] + rel1 * wce1[0] + bce[0];
        x[i][1] = t1 + rel0 * wce0[1] + rel1 * wce1[1] + bce[1];
        x[i][2] = t2 + rel0 * wce0[2] + rel1 * wce1[2] + bce[2];
        x[i][3] = t3 + rel0 * wce0[3] + rel1 * wce1[3] + bce[3];
    }

    // ---- helpers (R6 form: LN with gain/bias) ----
    auto lnorm = [&](float xv[4][4], float hv[4][4],
                     const float* __restrict__ gp, const float* __restrict__ bp) {
        float gj[4], bj[4];
        #pragma unroll
        for (int j = 0; j < 4; ++j) { gj[j] = gp[li + 16 * j]; bj[j] = bp[li + 16 * j]; }
        #pragma unroll
        for (int i = 0; i < 4; ++i) {
            float s = xv[i][0] + xv[i][1] + xv[i][2] + xv[i][3];
            float ss = xv[i][0] * xv[i][0] + xv[i][1] * xv[i][1]
                     + xv[i][2] * xv[i][2] + xv[i][3] * xv[i][3];
            #pragma unroll
            for (int m = 1; m < 16; m <<= 1) {
                s += __shfl_xor(s, m, 64);
                ss += __shfl_xor(ss, m, 64);
            }
            float mean = s * 0.015625f;
            float var = ss * 0.015625f - mean * mean;
            float rs = rsqrtf(var + 1e-5f);
            #pragma unroll
            for (int j = 0; j < 4; ++j)
                hv[i][j] = (xv[i][j] - mean) * rs * gj[j] + bj[j];
        }
    };

    auto put16 = [&](const float v[4][4]) {
        #pragma unroll
        for (int i = 0; i < 4; ++i) {
            int r = 4 * g + i;
            unsigned int u0, u1;
            asm("v_cvt_pk_bf16_f32 %0, %1, %2" : "=v"(u0) : "v"(v[i][0]), "v"(v[i][1]));
            asm("v_cvt_pk_bf16_f32 %0, %1, %2" : "=v"(u1) : "v"(v[i][2]), "v"(v[i][3]));
            *(uint2*)(sb + 128 * r + 16 * (((li >> 1)) ^ (r & 7)) + 8 * (li & 1))
                = make_uint2(u0, u1);
        }
        asm volatile("s_waitcnt lgkmcnt(0)" ::: "memory");
    };
    auto get_frags = [&](short8& a0, short8& a1) {
        a0 = *(const short8*)(sb + 128 * li + 16 * (g ^ (li & 7)));
        a1 = *(const short8*)(sb + 128 * li + 16 * ((4 + g) ^ (li & 7)));
    };

    auto gemm = [&](short8 a0, short8 a1, const short8* __restrict__ Wf, f32x4 acc[4]) {
        #pragma unroll
        for (int nt = 0; nt < 4; ++nt) {
            acc[nt] = __builtin_amdgcn_mfma_f32_16x16x32_bf16(a0, Wf[nt * 64 + lane], acc[nt], 0, 0, 0);
            acc[nt] = __builtin_amdgcn_mfma_f32_16x16x32_bf16(a1, Wf[(4 + nt) * 64 + lane], acc[nt], 0, 0, 0);
        }
    };

    const short8* Wq  = (const short8*)(wprep);
    const short8* Wk  = (const short8*)(wprep + 1 * 4096);
    const short8* Wv  = (const short8*)(wprep + 2 * 4096);
    const short8* Wo  = (const short8*)(wprep + 3 * 4096);
    const short8* Wm1 = (const short8*)(wprep + 4 * 4096);
    const short8* Wm2 = (const short8*)(wprep + 5 * 4096);
    const f32x4 z4 = {0.0f, 0.0f, 0.0f, 0.0f};

    // ---- LN1 + QKV ----
    float h[4][4];
    lnorm(x, h, ln1_g, ln1_b);
    short8 a0, a1;
    put16(h);
    get_frags(a0, a1);
    f32x4 qa[4], ka[4], va[4];
    #pragma unroll
    for (int t = 0; t < 4; ++t) { qa[t] = z4; ka[t] = z4; va[t] = z4; }
    gemm(a0, a1, Wq, qa);
    gemm(a0, a1, Wk, ka);
    gemm(a0, a1, Wv, va);

    // ---- attention: stage Q,K,V bf16 (Q aliases A-frag staging; same-wave DS order) ----
    #pragma unroll
    for (int nt = 0; nt < 4; ++nt) {
        int q = 4 * g + nt;
        int sw = q * 128 + ((li ^ (q & 7)) << 3);
        unsigned int uq0, uq1, uk0, uk1, uv0, uv1;
        asm("v_cvt_pk_bf16_f32 %0, %1, %2" : "=v"(uq0) : "v"(qa[nt][0]), "v"(qa[nt][1]));
        asm("v_cvt_pk_bf16_f32 %0, %1, %2" : "=v"(uq1) : "v"(qa[nt][2]), "v"(qa[nt][3]));
        asm("v_cvt_pk_bf16_f32 %0, %1, %2" : "=v"(uk0) : "v"(ka[nt][0]), "v"(ka[nt][1]));
        asm("v_cvt_pk_bf16_f32 %0, %1, %2" : "=v"(uk1) : "v"(ka[nt][2]), "v"(ka[nt][3]));
        asm("v_cvt_pk_bf16_f32 %0, %1, %2" : "=v"(uv0) : "v"(va[nt][0]), "v"(va[nt][1]));
        asm("v_cvt_pk_bf16_f32 %0, %1, %2" : "=v"(uv1) : "v"(va[nt][2]), "v"(va[nt][3]));
        *(uint2*)(sb + sw)        = make_uint2(uq0, uq1);
        *(uint2*)(sb + 2048 + sw) = make_uint2(uk0, uk1);
        *(uint2*)(sb + 4096 + sw) = make_uint2(uv0, uv1);
    }
    asm volatile("s_waitcnt lgkmcnt(0)" ::: "memory");

    // unit lane: token g, head hp = (lane&15)>>1, pos-half hf = lane&1
    const int hp = (lane & 15) >> 1;
    const int hf = lane & 1;
    const int qrow = 4 * g + (hp >> 1);      // staging row for nt = hp>>1
    const int lb = 8 * (hp & 1);             // li-base of this head's 8 d-chans
    float kk[8][4];
    float qq[8][2];
    #pragma unroll
    for (int d = 0; d < 8; ++d) {
        int sw = qrow * 128 + (((lb + d) ^ (qrow & 7)) << 3);
        uint2 uk = *(const uint2*)(sb + 2048 + sw);
        unsigned int uq = *(const unsigned int*)(sb + sw + 4 * hf);
        kk[d][0] = bflo(uk.x); kk[d][1] = bfhi(uk.x);
        kk[d][2] = bflo(uk.y); kk[d][3] = bfhi(uk.y);
        qq[d][0] = bflo(uq);   qq[d][1] = bfhi(uq);
    }
    float S[2][4], P[2][4];
    #pragma unroll
    for (int t = 0; t < 2; ++t)
        #pragma unroll
        for (int s = 0; s < 4; ++s) {
            float acc = qq[0][t] * kk[0][s];
            #pragma unroll
            for (int d = 1; d < 8; ++d) acc += qq[d][t] * kk[d][s];
            S[t][s] = acc;
        }
    #pragma unroll
    for (int t = 0; t < 2; ++t) {
        float m = fmaxf(fmaxf(S[t][0], S[t][1]), fmaxf(S[t][2], S[t][3]));
        float e0 = __expf((S[t][0] - m) * 0.35355339059327378f);
        float e1 = __expf((S[t][1] - m) * 0.35355339059327378f);
        float e2 = __expf((S[t][2] - m) * 0.35355339059327378f);
        float e3 = __expf((S[t][3] - m) * 0.35355339059327378f);
        float inv = 1.0f / (e0 + e1 + e2 + e3);
        P[t][0] = e0 * inv; P[t][1] = e1 * inv; P[t][2] = e2 * inv; P[t][3] = e3 * inv;
    }
    float vv[8][4];
    #pragma unroll
    for (int d = 0; d < 8; ++d) {
        int sw = qrow * 128 + (((lb + d) ^ (qrow & 7)) << 3);
        uint2 uv = *(const uint2*)(sb + 4096 + sw);
        vv[d][0] = bflo(uv.x); vv[d][1] = bfhi(uv.x);
        vv[d][2] = bflo(uv.y); vv[d][3] = bfhi(uv.y);
    }
    // O[t][d] -> A-frag staging: row r = 4g+2hf+t, chan c = 16*(hp>>1)+8*(hp&1)+d
    #pragma unroll
    for (int t = 0; t < 2; ++t) {
        int r = 4 * g + 2 * hf + t;
        #pragma unroll
        for (int d = 0; d < 8; ++d) {
            float O = P[t][0] * vv[d][0] + P[t][1] * vv[d][1]
                    + P[t][2] * vv[d][2] + P[t][3] * vv[d][3];
            unsigned int u;
            asm("v_cvt_pk_bf16_f32 %0, %1, %2" : "=v"(u) : "v"(O), "v"(O));
            int sidx = 4 * (hp & 1) + (d >> 1);
            int boff = 8 * (d & 1) + 2 * (hp >> 1);
            *(unsigned short*)(sb + 128 * r + 16 * (sidx ^ (r & 7)) + boff) = (unsigned short)u;
        }
    }
    asm volatile("s_waitcnt lgkmcnt(0)" ::: "memory");

    // ---- o @ w_o + b_o + residual ----
    get_frags(a0, a1);
    f32x4 oa[4];
    #pragma unroll
    for (int t = 0; t < 4; ++t) oa[t] = z4;
    gemm(a0, a1, Wo, oa);
    {
        float bo[4];
        #pragma unroll
        for (int j = 0; j < 4; ++j) bo[j] = b_o[li + 16 * j];
        #pragma unroll
        for (int i = 0; i < 4; ++i)
            #pragma unroll
            for (int j = 0; j < 4; ++j) x[i][j] += oa[j][i] + bo[j];
    }

    // ---- LN2 + MLP ----
    float h2[4][4];
    lnorm(x, h2, ln2_g, ln2_b);
    put16(h2);
    get_frags(a0, a1);
    f32x4 ma[4];
    #pragma unroll
    for (int t = 0; t < 4; ++t) ma[t] = z4;
    gemm(a0, a1, Wm1, ma);
    float g1[4][4];
    {
        float bm[4];
        #pragma unroll
        for (int j = 0; j < 4; ++j) bm[j] = b_m1[li + 16 * j];
        #pragma unroll
        for (int i = 0; i < 4; ++i)
            #pragma unroll
            for (int j = 0; j < 4; ++j) g1[i][j] = gelu_tanh(ma[j][i] + bm[j]);
    }
    put16(g1);
    get_frags(a0, a1);
    f32x4 m2a[4];
    #pragma unroll
    for (int t = 0; t < 4; ++t) m2a[t] = z4;
    gemm(a0, a1, Wm2, m2a);
    {
        float bm[4];
        #pragma unroll
        for (int j = 0; j < 4; ++j) bm[j] = b_m2[li + 16 * j];
        #pragma unroll
        for (int i = 0; i < 4; ++i)
            #pragma unroll
            for (int j = 0; j < 4; ++j) x[i][j] += m2a[j][i] + bm[j];
    }

    // ---- head softmax over 4 positions; weighted depth blend ----
    float wh[4];
    #pragma unroll
    for (int j = 0; j < 4; ++j) wh[j] = w_head[li + 16 * j];
    float lg[4];
    #pragma unroll
    for (int i = 0; i < 4; ++i) {
        float s = x[i][0] * wh[0] + x[i][1] * wh[1] + x[i][2] * wh[2] + x[i][3] * wh[3];
        #pragma unroll
        for (int m = 1; m < 16; m <<= 1) s += __shfl_xor(s, m, 64);
        lg[i] = s;
    }
    float m = fmaxf(fmaxf(lg[0], lg[1]), fmaxf(lg[2], lg[3]));
    float e0 = __expf(lg[0] - m), e1 = __expf(lg[1] - m);
    float e2 = __expf(lg[2] - m), e3 = __expf(lg[3] - m);
    float p0 = __shfl(predv, gbase + 0, 64);
    float p1 = __shfl(predv, gbase + 1, 64);
    float p2 = __shfl(predv, gbase + 2, 64);
    float p3 = __shfl(predv, gbase + 3, 64);
    float res = (p0 * e0 + p1 * e1 + p2 * e2 + p3 * e3) / (e0 + e1 + e2 + e3);
    if (li == 0) out[n] = res;
}

extern "C" void kernel_launch(void* const* d_in, const int* in_sizes, int n_in,
                              void* d_out, int out_size, void* d_ws, size_t ws_size,
                              hipStream_t stream) {
    const float* depth  = (const float*)d_in[0];
    const float* feat   = (const float*)d_in[1];
    const float* coord  = (const float*)d_in[2];
    const float* w_ce   = (const float*)d_in[3];
    const float* b_ce   = (const float*)d_in[4];
    const float* ln1_g  = (const float*)d_in[5];
    const float* ln1_b  = (const float*)d_in[6];
    const float* w_q    = (const float*)d_in[7];
    const float* w_k    = (const float*)d_in[8];
    const float* w_v    = (const float*)d_in[9];
    const float* w_o    = (const float*)d_in[10];
    const float* b_o    = (const float*)d_in[11];
    const float* ln2_g  = (const float*)d_in[12];
    const float* ln2_b  = (const float*)d_in[13];
    const float* w_m1   = (const float*)d_in[14];
    const float* b_m1   = (const float*)d_in[15];
    const float* w_m2   = (const float*)d_in[16];
    const float* b_m2   = (const float*)d_in[17];
    const float* w_head = (const float*)d_in[18];
    float* outp = (float*)d_out;

    unsigned short* wprep = (unsigned short*)d_ws;
    const size_t FEATT_OFF = 65536;                           // wprep uses 49152 B
    const size_t featT_bytes = (size_t)NB * NHW * 64 * 2;     // bf16
    unsigned int* featT = (unsigned int*)((char*)d_ws + FEATT_OFF);
    bool use_t = (d_ws != nullptr) && (ws_size >= FEATT_OFF + featT_bytes);

    wprep_kernel<<<48, 64, 0, stream>>>(w_q, w_k, w_v, w_o, w_m1, w_m2, wprep);
    if (use_t) {
        feat_transpose_kernel<<<NB * (NHW / 64), 256, 0, stream>>>(feat, featT);
        token_kernel<true><<<NTOK / 16, 256, 0, stream>>>(
            depth, feat, featT, coord, w_ce, b_ce, ln1_g, ln1_b,
            b_o, ln2_g, ln2_b, b_m1, b_m2, w_head, wprep, outp);
    } else {
        token_kernel<false><<<NTOK / 16, 256, 0, stream>>>(
            depth, feat, featT, coord, w_ce, b_ce, ln1_g, ln1_b,
            b_o, ln2_g, ln2_b, b_m1, b_m2, w_head, wprep, outp);
    }
}

// Round 10
// 120.510 us; speedup vs baseline: 1.0644x; 1.0039x over previous
//
#include <hip/hip_runtime.h>
#include <hip/hip_bf16.h>

#define NB 4
#define NQ 32768
#define NHW 65536
#define NTOK (NB * NQ)

typedef __attribute__((ext_vector_type(8))) short short8;   // 8 bf16 = 4 VGPR (MFMA A/B frag)
typedef __attribute__((ext_vector_type(4))) float f32x4;    // MFMA C/D frag

__device__ __forceinline__ unsigned short f2bf(float f) {
    unsigned int u = __float_as_uint(f);
    u = (u + 0x7FFFu + ((u >> 16) & 1u)) >> 16;   // RNE
    return (unsigned short)u;
}

__device__ __forceinline__ float bflo(unsigned int u) { return __uint_as_float(u << 16); }
__device__ __forceinline__ float bfhi(unsigned int u) { return __uint_as_float(u & 0xffff0000u); }

__device__ __forceinline__ float gelu_tanh(float u) {
    float z = 0.7978845608028654f * (u + 0.044715f * u * u * u);
    float e = __expf(2.0f * z);
    return u - u / (e + 1.0f);   // 0.5*u*(1+tanh(z)), overflow-safe
}

// (B,C,H,W) f32 -> (B,H*W,64) bf16, channel-permuted: chan c -> position p = 4*(c&15) + (c>>4)
__global__ __launch_bounds__(256) void feat_transpose_kernel(
        const float* __restrict__ feat, unsigned int* __restrict__ featT) {
    __shared__ float tile[64][65];
    int blk = blockIdx.x;
    int b = blk >> 10;
    int hw0 = (blk & 1023) << 6;
    int lane = threadIdx.x & 63;
    int row = threadIdx.x >> 6;
    const float* src = feat + ((size_t)b * 64) * NHW + hw0;
    #pragma unroll
    for (int cc = 0; cc < 16; ++cc) {
        int c = (cc << 2) + row;
        tile[c][lane] = src[(size_t)c * NHW + lane];
    }
    __syncthreads();
    unsigned int* dst = featT + ((size_t)(b * NHW + hw0)) * 32;
    #pragma unroll
    for (int it = 0; it < 8; ++it) {
        int flat = it * 256 + threadIdx.x;
        int w = flat >> 5, pp = flat & 31;        // u32 pp covers positions 2pp,2pp+1
        int c1 = (pp >> 1) + 32 * (pp & 1);       // chan of lo; hi chan = c1+16
        unsigned int u;
        asm("v_cvt_pk_bf16_f32 %0, %1, %2" : "=v"(u) : "v"(tile[c1][w]), "v"(tile[c1 + 16][w]));
        dst[(size_t)w * 32 + pp] = u;
    }
}

// Pack 6 weight matrices (64x64 f32 [k][n]) into bf16 B-fragment order with the
// k' permutation: k' = p, original k = (p&3)*16 + (p>>2).
__global__ __launch_bounds__(64) void wprep_kernel(
        const float* __restrict__ wq, const float* __restrict__ wk,
        const float* __restrict__ wv, const float* __restrict__ wo,
        const float* __restrict__ wm1, const float* __restrict__ wm2,
        unsigned short* __restrict__ out) {
    int bid = blockIdx.x;               // 48
    int mat = bid >> 3, ti = bid & 7;
    int kt = ti >> 2, nt = ti & 3;
    int l = threadIdx.x;
    const float* W = (mat == 0) ? wq : (mat == 1) ? wk : (mat == 2) ? wv
                   : (mat == 3) ? wo : (mat == 4) ? wm1 : wm2;
    unsigned short* dst = out + ((size_t)(bid) * 64 + l) * 8;
    #pragma unroll
    for (int j = 0; j < 8; ++j) {
        int kp = 8 * (l >> 4) + j + 32 * kt;       // permuted k'
        int k = ((kp & 3) << 4) + (kp >> 2);       // original chan
        int n = (l & 15) + 16 * nt;
        dst[j] = f2bf(W[k * 64 + n]);
    }
}

// One wave = 4 tokens (M=16 rows). Lane = (g = lane>>4 token, li = lane&15).
// D-layout: lane holds rows 4g+i, chans li+16*nt (staged at k'-pos 4li+nt).
// Per-wave LDS 6KB: [0,2KB) A-frag staging (aliases Q attn staging),
//                   [2KB,4KB) K staging, [4KB,6KB) V staging — all bf16.
template<bool USE_T>
__global__ __launch_bounds__(256, 2) void token_kernel(
    const float* __restrict__ depth, const float* __restrict__ feat,
    const unsigned int* __restrict__ featT, const float* __restrict__ coord,
    const float* __restrict__ w_ce, const float* __restrict__ b_ce,
    const float* __restrict__ ln1_g, const float* __restrict__ ln1_b,
    const float* __restrict__ b_o, const float* __restrict__ ln2_g,
    const float* __restrict__ ln2_b, const float* __restrict__ b_m1,
    const float* __restrict__ b_m2, const float* __restrict__ w_head,
    const unsigned short* __restrict__ wprep, float* __restrict__ out)
{
    __shared__ char smem[4 * 6144];
    const int wid = threadIdx.x >> 6;
    const int lane = threadIdx.x & 63;
    const int g = lane >> 4;
    const int li = lane & 15;
    const int n = ((blockIdx.x << 2) + wid) * 4 + g;
    const int b = n >> 15;
    char* sb = smem + wid * 6144;

    // ---- distributed gather: each lane computes ONE shifted-coord variant ----
    const float cy0 = coord[2 * n], cx0 = coord[2 * n + 1];
    float relv0, relv1, predv;
    int linv;
    {
        int v = li & 3;
        float vx = (v < 2) ? -1.0f : 1.0f;
        float vy = (v & 1) ? 1.0f : -1.0f;
        float cy = fminf(fmaxf(cy0 + vx * 0.00390625f + 1e-6f, -1.0f + 1e-6f), 1.0f - 1e-6f);
        float cx = fminf(fmaxf(cx0 + vy * 0.00390625f + 1e-6f, -1.0f + 1e-6f), 1.0f - 1e-6f);
        int iy = min(max((int)rintf((cy + 1.0f) * 128.0f - 0.5f), 0), 255);
        int ix = min(max((int)rintf((cx + 1.0f) * 128.0f - 0.5f), 0), 255);
        linv = iy * 256 + ix;
        predv = depth[(b << 16) + linv];
        float ysy = -0.99609375f + 0.0078125f * (float)iy;
        float xsx = -0.99609375f + 0.0078125f * (float)ix;
        relv0 = (cy0 - ysy) * 256.0f;
        relv1 = (cx0 - xsx) * 256.0f;
    }
    const int gbase = lane & 48;     // 16*g

    float wce0[4], wce1[4], bce[4];
    #pragma unroll
    for (int j = 0; j < 4; ++j) {
        wce0[j] = w_ce[li + 16 * j]; wce1[j] = w_ce[64 + li + 16 * j]; bce[j] = b_ce[li + 16 * j];
    }
    float x[4][4];
    #pragma unroll
    for (int i = 0; i < 4; ++i) {
        int lin = __shfl(linv, gbase + i, 64);
        float rel0 = __shfl(relv0, gbase + i, 64);
        float rel1 = __shfl(relv1, gbase + i, 64);
        float t0, t1, t2, t3;
        if (USE_T) {
            uint2 w = *(const uint2*)(featT + ((size_t)((b << 16) + lin)) * 32 + 2 * li);
            t0 = bflo(w.x); t1 = bfhi(w.x); t2 = bflo(w.y); t3 = bfhi(w.y);
        } else {
            t0 = feat[(((size_t)(b * 64 + li)) << 16) + lin];
            t1 = feat[(((size_t)(b * 64 + li + 16)) << 16) + lin];
            t2 = feat[(((size_t)(b * 64 + li + 32)) << 16) + lin];
            t3 = feat[(((size_t)(b * 64 + li + 48)) << 16) + lin];
        }
        x[i][0] = t0 + rel0 * wce0[0] + rel1 * wce1[0] + bce[0];
        x[i][1] = t1 + rel0 * wce0[1] + rel1 * wce1[1] + bce[1];
        x[i][2] = t2 + rel0 * wce0[2] + rel1 * wce1[2] + bce[2];
        x[i][3] = t3 + rel0 * wce0[3] + rel1 * wce1[3] + bce[3];
    }

    // ---- helpers ----
    auto lnorm = [&](float xv[4][4], float hv[4][4],
                     const float* __restrict__ gp, const float* __restrict__ bp) {
        float gj[4], bj[4];
        #pragma unroll
        for (int j = 0; j < 4; ++j) { gj[j] = gp[li + 16 * j]; bj[j] = bp[li + 16 * j]; }
        #pragma unroll
        for (int i = 0; i < 4; ++i) {
            float s = xv[i][0] + xv[i][1] + xv[i][2] + xv[i][3];
            float ss = xv[i][0] * xv[i][0] + xv[i][1] * xv[i][1]
                     + xv[i][2] * xv[i][2] + xv[i][3] * xv[i][3];
            #pragma unroll
            for (int m = 1; m < 16; m <<= 1) {
                s += __shfl_xor(s, m, 64);
                ss += __shfl_xor(ss, m, 64);
            }
            float mean = s * 0.015625f;
            float var = ss * 0.015625f - mean * mean;
            float rs = rsqrtf(var + 1e-5f);
            #pragma unroll
            for (int j = 0; j < 4; ++j)
                hv[i][j] = (xv[i][j] - mean) * rs * gj[j] + bj[j];
        }
    };

    auto put16 = [&](const float v[4][4]) {
        #pragma unroll
        for (int i = 0; i < 4; ++i) {
            int r = 4 * g + i;
            unsigned int u0, u1;
            asm("v_cvt_pk_bf16_f32 %0, %1, %2" : "=v"(u0) : "v"(v[i][0]), "v"(v[i][1]));
            asm("v_cvt_pk_bf16_f32 %0, %1, %2" : "=v"(u1) : "v"(v[i][2]), "v"(v[i][3]));
            *(uint2*)(sb + 128 * r + 16 * (((li >> 1)) ^ (r & 7)) + 8 * (li & 1))
                = make_uint2(u0, u1);
        }
        asm volatile("s_waitcnt lgkmcnt(0)" ::: "memory");
    };
    auto get_frags = [&](short8& a0, short8& a1) {
        a0 = *(const short8*)(sb + 128 * li + 16 * (g ^ (li & 7)));
        a1 = *(const short8*)(sb + 128 * li + 16 * ((4 + g) ^ (li & 7)));
    };

    // prefetch the kt=0 half of a weight matrix (4 frags = 16 VGPR)
    auto loadW4 = [&](const short8* __restrict__ Wf, short8 w[4]) {
        #pragma unroll
        for (int nt = 0; nt < 4; ++nt) w[nt] = Wf[nt * 64 + lane];
    };
    // gemm using prefetched kt=0 half; kt=1 half loaded here (hidden under MFMAs)
    auto gemm_pre = [&](short8 a0, short8 a1, const short8 wlo[4],
                        const short8* __restrict__ Wf, f32x4 acc[4]) {
        #pragma unroll
        for (int nt = 0; nt < 4; ++nt) {
            acc[nt] = __builtin_amdgcn_mfma_f32_16x16x32_bf16(a0, wlo[nt], acc[nt], 0, 0, 0);
            acc[nt] = __builtin_amdgcn_mfma_f32_16x16x32_bf16(a1, Wf[(4 + nt) * 64 + lane], acc[nt], 0, 0, 0);
        }
    };
    auto gemm = [&](short8 a0, short8 a1, const short8* __restrict__ Wf, f32x4 acc[4]) {
        #pragma unroll
        for (int nt = 0; nt < 4; ++nt) {
            acc[nt] = __builtin_amdgcn_mfma_f32_16x16x32_bf16(a0, Wf[nt * 64 + lane], acc[nt], 0, 0, 0);
            acc[nt] = __builtin_amdgcn_mfma_f32_16x16x32_bf16(a1, Wf[(4 + nt) * 64 + lane], acc[nt], 0, 0, 0);
        }
    };

    const short8* Wq  = (const short8*)(wprep);
    const short8* Wk  = (const short8*)(wprep + 1 * 4096);
    const short8* Wv  = (const short8*)(wprep + 2 * 4096);
    const short8* Wo  = (const short8*)(wprep + 3 * 4096);
    const short8* Wm1 = (const short8*)(wprep + 4 * 4096);
    const short8* Wm2 = (const short8*)(wprep + 5 * 4096);
    const f32x4 z4 = {0.0f, 0.0f, 0.0f, 0.0f};

    short8 wpre[4];

    // ---- LN1 + QKV ----
    float h[4][4];
    loadW4(Wq, wpre);              // prefetch Wq(kt=0) BEFORE the LN+put16 barrier
    lnorm(x, h, ln1_g, ln1_b);
    short8 a0, a1;
    put16(h);
    get_frags(a0, a1);
    f32x4 qa[4], ka[4], va[4];
    #pragma unroll
    for (int t = 0; t < 4; ++t) { qa[t] = z4; ka[t] = z4; va[t] = z4; }
    gemm_pre(a0, a1, wpre, Wq, qa);
    gemm(a0, a1, Wk, ka);          // no barrier between QKV gemms: compiler hoists freely
    gemm(a0, a1, Wv, va);

    // ---- attention: stage Q,K,V bf16 (Q aliases A-frag staging; same-wave DS order) ----
    #pragma unroll
    for (int nt = 0; nt < 4; ++nt) {
        int q = 4 * g + nt;
        int sw = q * 128 + ((li ^ (q & 7)) << 3);
        unsigned int uq0, uq1, uk0, uk1, uv0, uv1;
        asm("v_cvt_pk_bf16_f32 %0, %1, %2" : "=v"(uq0) : "v"(qa[nt][0]), "v"(qa[nt][1]));
        asm("v_cvt_pk_bf16_f32 %0, %1, %2" : "=v"(uq1) : "v"(qa[nt][2]), "v"(qa[nt][3]));
        asm("v_cvt_pk_bf16_f32 %0, %1, %2" : "=v"(uk0) : "v"(ka[nt][0]), "v"(ka[nt][1]));
        asm("v_cvt_pk_bf16_f32 %0, %1, %2" : "=v"(uk1) : "v"(ka[nt][2]), "v"(ka[nt][3]));
        asm("v_cvt_pk_bf16_f32 %0, %1, %2" : "=v"(uv0) : "v"(va[nt][0]), "v"(va[nt][1]));
        asm("v_cvt_pk_bf16_f32 %0, %1, %2" : "=v"(uv1) : "v"(va[nt][2]), "v"(va[nt][3]));
        *(uint2*)(sb + sw)        = make_uint2(uq0, uq1);
        *(uint2*)(sb + 2048 + sw) = make_uint2(uk0, uk1);
        *(uint2*)(sb + 4096 + sw) = make_uint2(uv0, uv1);
    }
    asm volatile("s_waitcnt lgkmcnt(0)" ::: "memory");

    // unit lane: token g, head hp = (lane&15)>>1, pos-half hf = lane&1
    const int hp = (lane & 15) >> 1;
    const int hf = lane & 1;
    const int qrow = 4 * g + (hp >> 1);      // staging row for nt = hp>>1
    const int lb = 8 * (hp & 1);             // li-base of this head's 8 d-chans
    float kk[8][4];
    float qq[8][2];
    #pragma unroll
    for (int d = 0; d < 8; ++d) {
        int sw = qrow * 128 + (((lb + d) ^ (qrow & 7)) << 3);
        uint2 uk = *(const uint2*)(sb + 2048 + sw);
        unsigned int uq = *(const unsigned int*)(sb + sw + 4 * hf);
        kk[d][0] = bflo(uk.x); kk[d][1] = bfhi(uk.x);
        kk[d][2] = bflo(uk.y); kk[d][3] = bfhi(uk.y);
        qq[d][0] = bflo(uq);   qq[d][1] = bfhi(uq);
    }
    float S[2][4], P[2][4];
    #pragma unroll
    for (int t = 0; t < 2; ++t)
        #pragma unroll
        for (int s = 0; s < 4; ++s) {
            float acc = qq[0][t] * kk[0][s];
            #pragma unroll
            for (int d = 1; d < 8; ++d) acc += qq[d][t] * kk[d][s];
            S[t][s] = acc;
        }
    #pragma unroll
    for (int t = 0; t < 2; ++t) {
        float m = fmaxf(fmaxf(S[t][0], S[t][1]), fmaxf(S[t][2], S[t][3]));
        float e0 = __expf((S[t][0] - m) * 0.35355339059327378f);
        float e1 = __expf((S[t][1] - m) * 0.35355339059327378f);
        float e2 = __expf((S[t][2] - m) * 0.35355339059327378f);
        float e3 = __expf((S[t][3] - m) * 0.35355339059327378f);
        float inv = 1.0f / (e0 + e1 + e2 + e3);
        P[t][0] = e0 * inv; P[t][1] = e1 * inv; P[t][2] = e2 * inv; P[t][3] = e3 * inv;
    }
    float vv[8][4];
    #pragma unroll
    for (int d = 0; d < 8; ++d) {
        int sw = qrow * 128 + (((lb + d) ^ (qrow & 7)) << 3);
        uint2 uv = *(const uint2*)(sb + 4096 + sw);
        vv[d][0] = bflo(uv.x); vv[d][1] = bfhi(uv.x);
        vv[d][2] = bflo(uv.y); vv[d][3] = bfhi(uv.y);
    }
    loadW4(Wo, wpre);              // prefetch Wo(kt=0) BEFORE the O-write barrier
    // O[t][d] -> A-frag staging: row r = 4g+2hf+t, chan c = 16*(hp>>1)+8*(hp&1)+d
    #pragma unroll
    for (int t = 0; t < 2; ++t) {
        int r = 4 * g + 2 * hf + t;
        #pragma unroll
        for (int d = 0; d < 8; ++d) {
            float O = P[t][0] * vv[d][0] + P[t][1] * vv[d][1]
                    + P[t][2] * vv[d][2] + P[t][3] * vv[d][3];
            unsigned int u;
            asm("v_cvt_pk_bf16_f32 %0, %1, %2" : "=v"(u) : "v"(O), "v"(O));
            int sidx = 4 * (hp & 1) + (d >> 1);
            int boff = 8 * (d & 1) + 2 * (hp >> 1);
            *(unsigned short*)(sb + 128 * r + 16 * (sidx ^ (r & 7)) + boff) = (unsigned short)u;
        }
    }
    asm volatile("s_waitcnt lgkmcnt(0)" ::: "memory");

    // ---- o @ w_o + b_o + residual ----
    get_frags(a0, a1);
    f32x4 oa[4];
    #pragma unroll
    for (int t = 0; t < 4; ++t) oa[t] = z4;
    gemm_pre(a0, a1, wpre, Wo, oa);
    {
        float bo[4];
        #pragma unroll
        for (int j = 0; j < 4; ++j) bo[j] = b_o[li + 16 * j];
        #pragma unroll
        for (int i = 0; i < 4; ++i)
            #pragma unroll
            for (int j = 0; j < 4; ++j) x[i][j] += oa[j][i] + bo[j];
    }

    // ---- LN2 + MLP ----
    float h2[4][4];
    loadW4(Wm1, wpre);             // prefetch Wm1(kt=0) BEFORE the LN2+put16 barrier
    lnorm(x, h2, ln2_g, ln2_b);
    put16(h2);
    get_frags(a0, a1);
    f32x4 ma[4];
    #pragma unroll
    for (int t = 0; t < 4; ++t) ma[t] = z4;
    gemm_pre(a0, a1, wpre, Wm1, ma);
    float g1[4][4];
    {
        float bm[4];
        #pragma unroll
        for (int j = 0; j < 4; ++j) bm[j] = b_m1[li + 16 * j];
        #pragma unroll
        for (int i = 0; i < 4; ++i)
            #pragma unroll
            for (int j = 0; j < 4; ++j) g1[i][j] = gelu_tanh(ma[j][i] + bm[j]);
    }
    loadW4(Wm2, wpre);             // prefetch Wm2(kt=0) BEFORE the g1 put16 barrier
    put16(g1);
    get_frags(a0, a1);
    f32x4 m2a[4];
    #pragma unroll
    for (int t = 0; t < 4; ++t) m2a[t] = z4;
    gemm_pre(a0, a1, wpre, Wm2, m2a);
    {
        float bm[4];
        #pragma unroll
        for (int j = 0; j < 4; ++j) bm[j] = b_m2[li + 16 * j];
        #pragma unroll
        for (int i = 0; i < 4; ++i)
            #pragma unroll
            for (int j = 0; j < 4; ++j) x[i][j] += m2a[j][i] + bm[j];
    }

    // ---- head softmax over 4 positions; weighted depth blend ----
    float wh[4];
    #pragma unroll
    for (int j = 0; j < 4; ++j) wh[j] = w_head[li + 16 * j];
    float lg[4];
    #pragma unroll
    for (int i = 0; i < 4; ++i) {
        float s = x[i][0] * wh[0] + x[i][1] * wh[1] + x[i][2] * wh[2] + x[i][3] * wh[3];
        #pragma unroll
        for (int m = 1; m < 16; m <<= 1) s += __shfl_xor(s, m, 64);
        lg[i] = s;
    }
    float m = fmaxf(fmaxf(lg[0], lg[1]), fmaxf(lg[2], lg[3]));
    float e0 = __expf(lg[0] - m), e1 = __expf(lg[1] - m);
    float e2 = __expf(lg[2] - m), e3 = __expf(lg[3] - m);
    float p0 = __shfl(predv, gbase + 0, 64);
    float p1 = __shfl(predv, gbase + 1, 64);
    float p2 = __shfl(predv, gbase + 2, 64);
    float p3 = __shfl(predv, gbase + 3, 64);
    float res = (p0 * e0 + p1 * e1 + p2 * e2 + p3 * e3) / (e0 + e1 + e2 + e3);
    if (li == 0) out[n] = res;
}

extern "C" void kernel_launch(void* const* d_in, const int* in_sizes, int n_in,
                              void* d_out, int out_size, void* d_ws, size_t ws_size,
                              hipStream_t stream) {
    const float* depth  = (const float*)d_in[0];
    const float* feat   = (const float*)d_in[1];
    const float* coord  = (const float*)d_in[2];
    const float* w_ce   = (const float*)d_in[3];
    const float* b_ce   = (const float*)d_in[4];
    const float* ln1_g  = (const float*)d_in[5];
    const float* ln1_b  = (const float*)d_in[6];
    const float* w_q    = (const float*)d_in[7];
    const float* w_k    = (const float*)d_in[8];
    const float* w_v    = (const float*)d_in[9];
    const float* w_o    = (const float*)d_in[10];
    const float* b_o    = (const float*)d_in[11];
    const float* ln2_g  = (const float*)d_in[12];
    const float* ln2_b  = (const float*)d_in[13];
    const float* w_m1   = (const float*)d_in[14];
    const float* b_m1   = (const float*)d_in[15];
    const float* w_m2   = (const float*)d_in[16];
    const float* b_m2   = (const float*)d_in[17];
    const float* w_head = (const float*)d_in[18];
    float* outp = (float*)d_out;

    unsigned short* wprep = (unsigned short*)d_ws;
    const size_t FEATT_OFF = 65536;                           // wprep uses 49152 B
    const size_t featT_bytes = (size_t)NB * NHW * 64 * 2;     // bf16
    unsigned int* featT = (unsigned int*)((char*)d_ws + FEATT_OFF);
    bool use_t = (d_ws != nullptr) && (ws_size >= FEATT_OFF + featT_bytes);

    wprep_kernel<<<48, 64, 0, stream>>>(w_q, w_k, w_v, w_o, w_m1, w_m2, wprep);
    if (use_t) {
        feat_transpose_kernel<<<NB * (NHW / 64), 256, 0, stream>>>(feat, featT);
        token_kernel<true><<<NTOK / 16, 256, 0, stream>>>(
            depth, feat, featT, coord, w_ce, b_ce, ln1_g, ln1_b,
            b_o, ln2_g, ln2_b, b_m1, b_m2, w_head, wprep, outp);
    } else {
        token_kernel<false><<<NTOK / 16, 256, 0, stream>>>(
            depth, feat, featT, coord, w_ce, b_ce, ln1_g, ln1_b,
            b_o, ln2_g, ln2_b, b_m1, b_m2, w_head, wprep, outp);
    }
}